// Round 7
// baseline (81.965 us; speedup 1.0000x reference)
//
#include <hip/hip_runtime.h>
#include <hip/hip_bf16.h>

typedef int   intx8   __attribute__((ext_vector_type(8)));
typedef float floatx4 __attribute__((ext_vector_type(4)));

static constexpr int TWO_B = 8192;   // 2*B rows
static constexpr int CDIM  = 128;    // feature dim
static constexpr int NSPL  = 32;     // column splits
// exp(x/T) = exp2(x * (1/T)/ln2), T = 0.5
#define SCALE 2.8853900817779268f
#define SQS   1.6986436f             // sqrt(SCALE): n8 rows pre-scaled by this,
                                     // so MFMA output is already in exp2 domain
#define INV_T 2.0f

#if __has_builtin(__builtin_amdgcn_exp2f)
#define EXP2F(x) __builtin_amdgcn_exp2f(x)
#else
#define EXP2F(x) exp2f(x)
#endif

// e8m0 scale byte 0x7F = 2^0 = 1.0 in all four byte slots
#define SCL1 0x7F7F7F7F

// ---------------------------------------------------------------------------
// Kernel 1: pair-structured normalize, 2 pairs per wave (512 blocks).
// Lanes 0-31 hold the zi row, lanes 32-63 the zj row. Computes per-half L2
// norm, fp32-exact positive dot (cross-half shuffle), fp8-e4m3 rows
// pre-scaled by sqrt(SCALE), and each row's self-sq from the STORED fp8
// bytes (exact cancellation vs the MFMA diagonal). Block 0 zeroes d_out for
// fk's atomic finish (stream ordering makes it visible to fk).
// ---------------------------------------------------------------------------
__global__ __launch_bounds__(256) void nk(const float* __restrict__ zi,
                                          const float* __restrict__ zj,
                                          unsigned char* __restrict__ n8,
                                          float* __restrict__ posv,
                                          float* __restrict__ sqv,
                                          float* __restrict__ outz) {
    if (blockIdx.x == 0 && threadIdx.x == 0) *outz = 0.0f;
    const int w = threadIdx.x >> 6, lane = threadIdx.x & 63;
    const int half = lane >> 5;            // 0: zi row, 1: zj row
    const int l32  = lane & 31;
#pragma unroll
    for (int pi = 0; pi < 2; ++pi) {
        const int pr = (blockIdx.x * 4 + w) * 2 + pi;   // pair index 0..4095
        const float* src = half ? (zj + (size_t)pr * CDIM) : (zi + (size_t)pr * CDIM);
        float4 x = reinterpret_cast<const float4*>(src)[l32];
        float ss = x.x * x.x + x.y * x.y + x.z * x.z + x.w * x.w;
#pragma unroll
        for (int m = 1; m < 32; m <<= 1) ss += __shfl_xor(ss, m, 64);  // within-half
        const float rn = rsqrtf(ss);
        float4 y; y.x = x.x * rn; y.y = x.y * rn; y.z = x.z * rn; y.w = x.w * rn;

        // fp32-exact positive dot: cross-half partner lanes.
        const float qx = __shfl_xor(y.x, 32, 64);
        const float qy = __shfl_xor(y.y, 32, 64);
        const float qz = __shfl_xor(y.z, 32, 64);
        const float qw = __shfl_xor(y.w, 32, 64);
        float d = y.x * qx + y.y * qy + y.z * qz + y.w * qw;
#pragma unroll
        for (int m = 1; m < 32; m <<= 1) d += __shfl_xor(d, m, 64);

        // fp8 row, pre-scaled so MFMA output is SCALE*sim.
        int p = __builtin_amdgcn_cvt_pk_fp8_f32(y.x * SQS, y.y * SQS, 0, false);
        p     = __builtin_amdgcn_cvt_pk_fp8_f32(y.z * SQS, y.w * SQS, p, true);
        const int row = pr + half * 4096;
        reinterpret_cast<int*>(n8 + (size_t)row * CDIM)[l32] = p;

        // self-sq from the stored bytes (already in exp2 domain).
        const float f0 = __builtin_amdgcn_cvt_f32_fp8(p, 0);
        const float f1 = __builtin_amdgcn_cvt_f32_fp8(p, 1);
        const float f2 = __builtin_amdgcn_cvt_f32_fp8(p, 2);
        const float f3 = __builtin_amdgcn_cvt_f32_fp8(p, 3);
        float sq = f0 * f0 + f1 * f1 + f2 * f2 + f3 * f3;
#pragma unroll
        for (int m = 1; m < 32; m <<= 1) sq += __shfl_xor(sq, m, 64);

        if (l32 == 0) { posv[row] = d; sqv[row] = sq; }
    }
}

// ---------------------------------------------------------------------------
// Kernel 2: per-row sum of 2^(SCALE*sim) over a 256-column slice, via
// MX-scaled fp8 MFMA (K=128 in ONE instruction, scales = 1.0).
// BARRIER-FREE: B-fragments are loaded straight from global — the wave's
// access (row=colbase+ni*16+l15, k=lg*32) covers a contiguous 2 KB block,
// perfectly coalesced, and n8 (1 MB) is L2-resident. No LDS, no syncthreads,
// no vmcnt(0) drains. 4 waves/SIMD (grid 32x32, 4 blocks/CU) hide latency.
// Wave w -> rows w*64..+64 (4 m-subtiles; each B-frag feeds 4 MFMAs).
// ---------------------------------------------------------------------------
__global__ __launch_bounds__(256, 4) void sk(const unsigned char* __restrict__ n8,
                                             float* __restrict__ partial) {
    const int rt  = blockIdx.x;   // 0..31
    const int csp = blockIdx.y;   // 0..NSPL-1
    const int w   = (threadIdx.x >> 6);
    const int lane = threadIdx.x & 63;
    const int l15 = lane & 15;
    const int lg  = lane >> 4;

    // A fragments: 64 rows x 128 k per wave, registers.
    // f8f6f4 16x16x128 A-layout: m = lane&15, k = (lane>>4)*32 + j
    const int rowbase = rt * 256 + w * 64;
    intx8 afrag[4];
#pragma unroll
    for (int mi = 0; mi < 4; ++mi)
        afrag[mi] = *reinterpret_cast<const intx8*>(
            n8 + (size_t)(rowbase + mi * 16 + l15) * CDIM + lg * 32);

    float rowsum[4][4];
#pragma unroll
    for (int mi = 0; mi < 4; ++mi)
#pragma unroll
        for (int r = 0; r < 4; ++r) rowsum[mi][r] = 0.0f;

    const int colbase = csp * 256;
#pragma unroll 4
    for (int ni = 0; ni < 16; ++ni) {
        // B-layout: n = lane&15 (col row), k = (lane>>4)*32 + j
        intx8 bfrag = *reinterpret_cast<const intx8*>(
            n8 + (size_t)(colbase + ni * 16 + l15) * CDIM + lg * 32);
#pragma unroll
        for (int mi = 0; mi < 4; ++mi) {
            floatx4 acc = {0.f, 0.f, 0.f, 0.f};
            acc = __builtin_amdgcn_mfma_scale_f32_16x16x128_f8f6f4(
                afrag[mi], bfrag, acc, 0, 0, 0, SCL1, 0, SCL1);
            // C/D layout: col = lane&15, row = (lane>>4)*4 + reg
#pragma unroll
            for (int r = 0; r < 4; ++r)
                rowsum[mi][r] += EXP2F(acc[r]);   // acc is already SCALE*sim
        }
    }

    // Sum across the 16 column-lanes within each lane-group.
#pragma unroll
    for (int mi = 0; mi < 4; ++mi)
#pragma unroll
        for (int r = 0; r < 4; ++r) {
            float v = rowsum[mi][r];
            v += __shfl_xor(v, 1, 64);
            v += __shfl_xor(v, 2, 64);
            v += __shfl_xor(v, 4, 64);
            v += __shfl_xor(v, 8, 64);
            rowsum[mi][r] = v;
        }
    if (l15 == 0) {
#pragma unroll
        for (int mi = 0; mi < 4; ++mi)
#pragma unroll
            for (int r = 0; r < 4; ++r)
                partial[csp * TWO_B + rowbase + mi * 16 + lg * 4 + r] = rowsum[mi][r];
    }
}

// ---------------------------------------------------------------------------
// Kernel 3: thread-per-row finalize + fused mean. 32 blocks x 256 rows:
//   S = sum_c partial[c][row] + 2^(SCALE*pos) - 2^sq
//   loss_r = ln(S) - pos/T;  block-reduce; 32 atomicAdds into d_out
//   (zeroed by nk; 32 same-address atomics ~0.3us — R3's failure was 2048).
// ---------------------------------------------------------------------------
__global__ __launch_bounds__(256) void fk(const float* __restrict__ partial,
                                          const float* __restrict__ posv,
                                          const float* __restrict__ sqv,
                                          float* __restrict__ out) {
    const int row = blockIdx.x * 256 + threadIdx.x;
    float S = 0.0f;
#pragma unroll
    for (int c = 0; c < NSPL; ++c) S += partial[c * TWO_B + row];
    const float pos = posv[row], sq = sqv[row];
    S += EXP2F(pos * SCALE) - EXP2F(sq);
    float loss = __logf(S) - pos * INV_T;
#pragma unroll
    for (int m = 1; m < 64; m <<= 1) loss += __shfl_xor(loss, m, 64);
    __shared__ float acc[4];
    if ((threadIdx.x & 63) == 0) acc[threadIdx.x >> 6] = loss;
    __syncthreads();
    if (threadIdx.x == 0)
        atomicAdd(out, (acc[0] + acc[1] + acc[2] + acc[3]) * (1.0f / TWO_B));
}

extern "C" void kernel_launch(void* const* d_in, const int* in_sizes, int n_in,
                              void* d_out, int out_size, void* d_ws, size_t ws_size,
                              hipStream_t stream) {
    const float* zi = (const float*)d_in[0];
    const float* zj = (const float*)d_in[1];
    char* ws = (char*)d_ws;
    unsigned char* n8      = (unsigned char*)ws;                         // 1 MB
    float*         partial = (float*)(ws + (size_t)TWO_B * CDIM);        // 1 MB (32 splits)
    float*         posv    = (float*)(ws + (size_t)TWO_B * CDIM + (size_t)NSPL * TWO_B * 4);
    float*         sqv     = posv + TWO_B;                               // 32 KB each

    nk<<<TWO_B / 16, 256, 0, stream>>>(zi, zj, n8, posv, sqv, (float*)d_out);
    sk<<<dim3(32, NSPL), 256, 0, stream>>>(n8, partial);
    fk<<<32, 256, 0, stream>>>(partial, posv, sqv, (float*)d_out);
}

// Round 8
// 76.637 us; speedup vs baseline: 1.0695x; 1.0695x over previous
//
#include <hip/hip_runtime.h>
#include <hip/hip_bf16.h>

typedef int   intx8   __attribute__((ext_vector_type(8)));
typedef int   intx4   __attribute__((ext_vector_type(4)));
typedef float floatx4 __attribute__((ext_vector_type(4)));

static constexpr int TWO_B = 8192;   // 2*B rows
static constexpr int CDIM  = 128;    // feature dim
static constexpr int NSPL  = 16;     // column splits (R6-proven)
// exp(x/T) = exp2(x * (1/T)/ln2), T = 0.5
#define SCALE 2.8853900817779268f
#define SQS   1.6986436f             // sqrt(SCALE): n8 rows pre-scaled by this,
                                     // so MFMA output is already in exp2 domain
#define INV_T 2.0f

#if __has_builtin(__builtin_amdgcn_exp2f)
#define EXP2F(x) __builtin_amdgcn_exp2f(x)
#else
#define EXP2F(x) exp2f(x)
#endif

// e8m0 scale byte 0x7F = 2^0 = 1.0 in all four byte slots
#define SCL1 0x7F7F7F7F

// ---------------------------------------------------------------------------
// Kernel 1: pair-structured normalize, 2 pairs per wave (512 blocks).
// Lanes 0-31 hold the zi row, lanes 32-63 the zj row. Computes per-half L2
// norm, fp32-exact positive dot (cross-half shuffle), fp8-e4m3 rows
// pre-scaled by sqrt(SCALE), and each row's self-sq from the STORED fp8
// bytes (exact cancellation vs the MFMA diagonal). Block 0 zeroes d_out for
// fk's atomic finish.
// ---------------------------------------------------------------------------
__global__ __launch_bounds__(256) void nk(const float* __restrict__ zi,
                                          const float* __restrict__ zj,
                                          unsigned char* __restrict__ n8,
                                          float* __restrict__ posv,
                                          float* __restrict__ sqv,
                                          float* __restrict__ outz) {
    if (blockIdx.x == 0 && threadIdx.x == 0) *outz = 0.0f;
    const int w = threadIdx.x >> 6, lane = threadIdx.x & 63;
    const int half = lane >> 5;            // 0: zi row, 1: zj row
    const int l32  = lane & 31;
#pragma unroll
    for (int pi = 0; pi < 2; ++pi) {
        const int pr = (blockIdx.x * 4 + w) * 2 + pi;   // pair index 0..4095
        const float* src = half ? (zj + (size_t)pr * CDIM) : (zi + (size_t)pr * CDIM);
        float4 x = reinterpret_cast<const float4*>(src)[l32];
        float ss = x.x * x.x + x.y * x.y + x.z * x.z + x.w * x.w;
#pragma unroll
        for (int m = 1; m < 32; m <<= 1) ss += __shfl_xor(ss, m, 64);  // within-half
        const float rn = rsqrtf(ss);
        float4 y; y.x = x.x * rn; y.y = x.y * rn; y.z = x.z * rn; y.w = x.w * rn;

        // fp32-exact positive dot: cross-half partner lanes.
        const float qx = __shfl_xor(y.x, 32, 64);
        const float qy = __shfl_xor(y.y, 32, 64);
        const float qz = __shfl_xor(y.z, 32, 64);
        const float qw = __shfl_xor(y.w, 32, 64);
        float d = y.x * qx + y.y * qy + y.z * qz + y.w * qw;
#pragma unroll
        for (int m = 1; m < 32; m <<= 1) d += __shfl_xor(d, m, 64);

        // fp8 row, pre-scaled so MFMA output is SCALE*sim.
        int p = __builtin_amdgcn_cvt_pk_fp8_f32(y.x * SQS, y.y * SQS, 0, false);
        p     = __builtin_amdgcn_cvt_pk_fp8_f32(y.z * SQS, y.w * SQS, p, true);
        const int row = pr + half * 4096;
        reinterpret_cast<int*>(n8 + (size_t)row * CDIM)[l32] = p;

        // self-sq from the stored bytes (already in exp2 domain).
        const float f0 = __builtin_amdgcn_cvt_f32_fp8(p, 0);
        const float f1 = __builtin_amdgcn_cvt_f32_fp8(p, 1);
        const float f2 = __builtin_amdgcn_cvt_f32_fp8(p, 2);
        const float f3 = __builtin_amdgcn_cvt_f32_fp8(p, 3);
        float sq = f0 * f0 + f1 * f1 + f2 * f2 + f3 * f3;
#pragma unroll
        for (int m = 1; m < 32; m <<= 1) sq += __shfl_xor(sq, m, 64);

        if (l32 == 0) { posv[row] = d; sqv[row] = sq; }
    }
}

// ---------------------------------------------------------------------------
// Kernel 2 [R6-proven, verbatim]: per-row sum of 2^(SCALE*sim) over a
// 512-column slice, via MX-scaled fp8 MFMA (K=128 in ONE instruction,
// scales = 1.0). Block = 256 thr (4 waves), 256 rows/block (wave w -> rows
// w*64..+64, 4 m-subtiles; each B-frag feeds 4 MFMAs). Columns streamed in
// 64-wide stages (8 KB LDS) via global_load_lds 16B, global-side XOR
// swizzle. Grid (32,16); partials per (split,row); no atomics.
// R7's barrier-free global-B variant was +4us — LDS broadcast staging wins
// when 4 waves share each tile.
// ---------------------------------------------------------------------------
__global__ __launch_bounds__(256) void sk(const unsigned char* __restrict__ n8,
                                          float* __restrict__ partial) {
    const int rt  = blockIdx.x;   // 0..31
    const int csp = blockIdx.y;   // 0..15
    const int tid = threadIdx.x;
    const int w   = tid >> 6;
    const int lane = tid & 63;
    const int l15 = lane & 15;
    const int lg  = lane >> 4;

    __shared__ unsigned char ldsB[64 * CDIM];   // 8 KB (fp8)

    // A fragments: 64 rows x 128 k per wave, registers.
    // f8f6f4 16x16x128 A-layout: m = lane&15, k = (lane>>4)*32 + j
    const int rowbase = rt * 256 + w * 64;
    intx8 afrag[4];
#pragma unroll
    for (int mi = 0; mi < 4; ++mi)
        afrag[mi] = *reinterpret_cast<const intx8*>(
            n8 + (size_t)(rowbase + mi * 16 + l15) * CDIM + lg * 32);

    float rowsum[4][4];
#pragma unroll
    for (int mi = 0; mi < 4; ++mi)
#pragma unroll
        for (int r = 0; r < 4; ++r) rowsum[mi][r] = 0.0f;

    const int colbase0 = csp * 512;
    for (int ct = 0; ct < 8; ++ct) {
        const int colbase = colbase0 + ct * 64;
        __syncthreads();   // previous stage's compute done before overwrite
        // Stage 64 rows x 128 B. LDS 16B-slot s holds global chunk
        // (R = s>>3, c = (s&7) ^ (R&7)) — swizzle on the global side.
#pragma unroll
        for (int i = 0; i < 2; ++i) {
            const int s = i * 256 + tid;          // uniform base + lane*16
            const int R = s >> 3, cs = s & 7;
            const int gc = cs ^ (R & 7);
            const unsigned char* g = n8 + (size_t)(colbase + R) * CDIM + gc * 16;
            __builtin_amdgcn_global_load_lds(
                (__attribute__((address_space(1))) void*)g,
                (__attribute__((address_space(3))) void*)(ldsB + s * 16),
                16, 0, 0);
        }
        __syncthreads();   // vmcnt(0) drain before barrier

#pragma unroll
        for (int ni = 0; ni < 4; ++ni) {
            // B-layout: n = lane&15 (local row R), k = (lane>>4)*32 + j
            const int R  = ni * 16 + l15;
            const int c0 = lg * 2;
            const int p0 = R * 8 + (c0 ^ (R & 7));
            const int p1 = R * 8 + ((c0 + 1) ^ (R & 7));
            intx4 blo = *reinterpret_cast<const intx4*>(ldsB + p0 * 16);
            intx4 bhi = *reinterpret_cast<const intx4*>(ldsB + p1 * 16);
            intx8 bfrag;
            bfrag[0] = blo[0]; bfrag[1] = blo[1]; bfrag[2] = blo[2]; bfrag[3] = blo[3];
            bfrag[4] = bhi[0]; bfrag[5] = bhi[1]; bfrag[6] = bhi[2]; bfrag[7] = bhi[3];
#pragma unroll
            for (int mi = 0; mi < 4; ++mi) {
                floatx4 acc = {0.f, 0.f, 0.f, 0.f};
                acc = __builtin_amdgcn_mfma_scale_f32_16x16x128_f8f6f4(
                    afrag[mi], bfrag, acc, 0, 0, 0, SCL1, 0, SCL1);
                // C/D layout: col = lane&15, row = (lane>>4)*4 + reg
#pragma unroll
                for (int r = 0; r < 4; ++r)
                    rowsum[mi][r] += EXP2F(acc[r]);   // acc is already SCALE*sim
            }
        }
    }

    // Sum across the 16 column-lanes within each lane-group.
#pragma unroll
    for (int mi = 0; mi < 4; ++mi)
#pragma unroll
        for (int r = 0; r < 4; ++r) {
            float v = rowsum[mi][r];
            v += __shfl_xor(v, 1, 64);
            v += __shfl_xor(v, 2, 64);
            v += __shfl_xor(v, 4, 64);
            v += __shfl_xor(v, 8, 64);
            rowsum[mi][r] = v;
        }
    if (l15 == 0) {
#pragma unroll
        for (int mi = 0; mi < 4; ++mi)
#pragma unroll
            for (int r = 0; r < 4; ++r)
                partial[csp * TWO_B + rowbase + mi * 16 + lg * 4 + r] = rowsum[mi][r];
    }
}

// ---------------------------------------------------------------------------
// Kernel 3: thread-per-row finalize + fused mean. 32 blocks x 256 rows:
//   S = sum_c partial[c][row] + 2^(SCALE*pos) - 2^sq
//   loss_r = ln(S) - pos/T;  block-reduce; 32 atomicAdds into d_out
//   (zeroed by nk; 32 same-address atomics ~0.3us — R3's failure was 2048).
// ---------------------------------------------------------------------------
__global__ __launch_bounds__(256) void fk(const float* __restrict__ partial,
                                          const float* __restrict__ posv,
                                          const float* __restrict__ sqv,
                                          float* __restrict__ out) {
    const int row = blockIdx.x * 256 + threadIdx.x;
    float S = 0.0f;
#pragma unroll
    for (int c = 0; c < NSPL; ++c) S += partial[c * TWO_B + row];
    const float pos = posv[row], sq = sqv[row];
    S += EXP2F(pos * SCALE) - EXP2F(sq);
    float loss = __logf(S) - pos * INV_T;
#pragma unroll
    for (int m = 1; m < 64; m <<= 1) loss += __shfl_xor(loss, m, 64);
    __shared__ float acc[4];
    if ((threadIdx.x & 63) == 0) acc[threadIdx.x >> 6] = loss;
    __syncthreads();
    if (threadIdx.x == 0)
        atomicAdd(out, (acc[0] + acc[1] + acc[2] + acc[3]) * (1.0f / TWO_B));
}

extern "C" void kernel_launch(void* const* d_in, const int* in_sizes, int n_in,
                              void* d_out, int out_size, void* d_ws, size_t ws_size,
                              hipStream_t stream) {
    const float* zi = (const float*)d_in[0];
    const float* zj = (const float*)d_in[1];
    char* ws = (char*)d_ws;
    unsigned char* n8      = (unsigned char*)ws;                         // 1 MB
    float*         partial = (float*)(ws + (size_t)TWO_B * CDIM);        // 512 KB
    float*         posv    = (float*)(ws + (size_t)TWO_B * CDIM + (size_t)NSPL * TWO_B * 4);
    float*         sqv     = posv + TWO_B;                               // 32 KB each

    nk<<<TWO_B / 16, 256, 0, stream>>>(zi, zj, n8, posv, sqv, (float*)d_out);
    sk<<<dim3(32, NSPL), 256, 0, stream>>>(n8, partial);
    fk<<<32, 256, 0, stream>>>(partial, posv, sqv, (float*)d_out);
}